// Round 6
// baseline (268.830 us; speedup 1.0000x reference)
//
#include <hip/hip_runtime.h>
#include <math.h>

// Problem constants
#define BATCH   8
#define LSEQ    4096      // 64*64
#define CMODEL  128
#define DIN     256
#define NSTATE  16
#define RRANK   8
#define NCH     128       // chunks per sequence
#define TCH     32        // timesteps per chunk (NCH*TCH == LSEQ)

typedef __attribute__((ext_vector_type(8))) short short8;
typedef __attribute__((ext_vector_type(4))) float f32x4;

__device__ __forceinline__ float sigmoid_fast(float x) {
    return __builtin_amdgcn_rcpf(1.0f + __expf(-x));
}
__device__ __forceinline__ float silu_fast(float x) { return x * sigmoid_fast(x); }
__device__ __forceinline__ float softplus_fast(float x) {
    return fmaxf(x, 0.0f) + __logf(1.0f + __expf(-fabsf(x)));
}
__device__ __forceinline__ unsigned short f2bf(float f) {
    unsigned u = __float_as_uint(f);
    return (unsigned short)((u + 0x7FFFu + ((u >> 16) & 1u)) >> 16);   // RNE
}

// dA[n] = exp(dtv*A[n]); A[n] == (n+1)*A[0] fast path: 1 exp + mul chain.
__device__ __forceinline__ void dA_powers(float dtv, const float* A, bool fast,
                                          float* dA)
{
    if (fast) {
        float e1 = __expf(dtv * A[0]);
        float e2 = e1 * e1;
        float e4 = e2 * e2;
        float e8 = e4 * e4;
        dA[0] = e1;        dA[1] = e2;        dA[2] = e2 * e1;   dA[3] = e4;
        dA[4] = e4 * e1;   dA[5] = e4 * e2;   dA[6] = e4 * dA[2]; dA[7] = e8;
        dA[8] = e8 * e1;   dA[9] = e8 * e2;   dA[10] = e8 * dA[2]; dA[11] = e8 * e4;
        dA[12] = e8 * dA[4]; dA[13] = e8 * dA[5]; dA[14] = e8 * dA[6]; dA[15] = e8 * e8;
    } else {
        #pragma unroll
        for (int n = 0; n < 16; ++n) dA[n] = __expf(dtv * A[n]);
    }
}

#define LSTR 72   // LDS row stride (bf16 units): 64 data + 8 pad; 2-way max = free

// ---------------------------------------------------------------------------
// K0: one-shot setup. 64x64 transpose+bf16-convert tiles:
//   blocks [0,1024):   x_hsi[b,c,l] -> xbf[b,l,c]
//   blocks [1024,1040): W_in[c,j]   -> Wt_in[j,c]
//   blocks [1040,1048): W_out[k,c]  -> Wt_out[c,k]
//   block 1048: zero part[64]
// grid 1049, block 256
// ---------------------------------------------------------------------------
__device__ __forceinline__ void tr64_bf(const float* __restrict__ src, int lds,
                                        int r0, int c0,
                                        unsigned short* __restrict__ dst, int ldd)
{
    __shared__ float ts[64][65];
    const int tid = threadIdx.x;
    #pragma unroll
    for (int it = 0; it < 4; ++it) {
        int slot = tid + it * 256;
        int i = slot >> 4, j4 = slot & 15;
        float4 v = *(const float4*)&src[(size_t)(r0 + i) * lds + c0 + j4 * 4];
        ts[i][j4*4+0] = v.x; ts[i][j4*4+1] = v.y;
        ts[i][j4*4+2] = v.z; ts[i][j4*4+3] = v.w;
    }
    __syncthreads();
    #pragma unroll
    for (int it = 0; it < 4; ++it) {
        int slot = tid + it * 256;
        int row = slot >> 4, c4 = slot & 15;
        ushort4 o;
        o.x = f2bf(ts[c4*4+0][row]);
        o.y = f2bf(ts[c4*4+1][row]);
        o.z = f2bf(ts[c4*4+2][row]);
        o.w = f2bf(ts[c4*4+3][row]);
        *(ushort4*)&dst[(size_t)(c0 + row) * ldd + r0 + c4 * 4] = o;
    }
}

__global__ __launch_bounds__(256) void k0_setup(
    const float* __restrict__ x_hsi, const float* __restrict__ W_in,
    const float* __restrict__ W_out,
    unsigned short* __restrict__ xbf, unsigned short* __restrict__ wtin,
    unsigned short* __restrict__ wtout, float* __restrict__ part)
{
    const int bid = blockIdx.x;
    if (bid < 1024) {
        int b = bid >> 7, sub = bid & 127;
        int lt = sub & 63, ct = sub >> 6;
        tr64_bf(x_hsi + (size_t)b * 524288, 4096, ct * 64, lt * 64,
                xbf + (size_t)b * 524288, 128);
    } else if (bid < 1040) {
        int t2 = bid - 1024;
        int ct = t2 >> 3, jt = t2 & 7;
        tr64_bf(W_in, 512, ct * 64, jt * 64, wtin, 128);
    } else if (bid < 1048) {
        int t3 = bid - 1040;
        int kt = t3 >> 1, ct = t3 & 1;
        tr64_bf(W_out, 128, kt * 64, ct * 64, wtout, 256);
    } else {
        if (threadIdx.x < 64) part[threadIdx.x] = 0.0f;
    }
}

// ---------------------------------------------------------------------------
// K1 (MFMA bf16): xz = x @ W_in. 128(l) x 128(j) tile, K=128 in chunks of 64.
// A <- xbf[row][c] direct; B <- Wt_in[j][c] direct. 4 waves x 64x64 quadrant.
// grid (256, 4), block 256
// ---------------------------------------------------------------------------
__global__ __launch_bounds__(256) void k1_gemm_in(
    const unsigned short* __restrict__ xbf, const unsigned short* __restrict__ wtin,
    float* __restrict__ xh_raw, float* __restrict__ z_silu)
{
    __shared__ __align__(16) unsigned short Abf[128 * LSTR];
    __shared__ __align__(16) unsigned short Bbf[128 * LSTR];
    const int tid = threadIdx.x;
    const int R0  = blockIdx.x * 128;         // global row (b*L + l)
    const int j0  = blockIdx.y * 128;

    const int w    = tid >> 6;
    const int lane = tid & 63;
    const int lm   = lane & 15;
    const int q    = lane >> 4;
    const int mbase = (w & 1) * 64;           // l-quadrant
    const int nbase = (w >> 1) * 64;          // j-quadrant

    f32x4 acc[4][4];
    #pragma unroll
    for (int i = 0; i < 4; ++i)
        #pragma unroll
        for (int j = 0; j < 4; ++j) acc[i][j] = (f32x4){0.f, 0.f, 0.f, 0.f};

    for (int kc = 0; kc < 128; kc += 64) {
        __syncthreads();
        #pragma unroll
        for (int it = 0; it < 4; ++it) {
            int slot = tid + it * 256;        // 1024 slots: 128 rows x 8 segs
            int r = slot >> 3, seg = slot & 7;
            short8 va = *(const short8*)&xbf[(size_t)(R0 + r) * 128 + kc + seg * 8];
            *(short8*)&Abf[r * LSTR + seg * 8] = va;
            short8 vb = *(const short8*)&wtin[(size_t)(j0 + r) * 128 + kc + seg * 8];
            *(short8*)&Bbf[r * LSTR + seg * 8] = vb;
        }
        __syncthreads();
        #pragma unroll
        for (int kt = 0; kt < 2; ++kt) {
            short8 af[4], bfr[4];
            #pragma unroll
            for (int mt = 0; mt < 4; ++mt)
                af[mt] = *(const short8*)&Abf[(mbase + mt * 16 + lm) * LSTR + kt * 32 + q * 8];
            #pragma unroll
            for (int nt = 0; nt < 4; ++nt)
                bfr[nt] = *(const short8*)&Bbf[(nbase + nt * 16 + lm) * LSTR + kt * 32 + q * 8];
            #pragma unroll
            for (int mt = 0; mt < 4; ++mt)
                #pragma unroll
                for (int nt = 0; nt < 4; ++nt)
                    acc[mt][nt] = __builtin_amdgcn_mfma_f32_16x16x32_bf16(
                        af[mt], bfr[nt], acc[mt][nt], 0, 0, 0);
        }
    }

    const bool is_xh = (j0 < 256);
    #pragma unroll
    for (int mt = 0; mt < 4; ++mt) {
        #pragma unroll
        for (int r = 0; r < 4; ++r) {
            int row = R0 + mbase + mt * 16 + q * 4 + r;
            #pragma unroll
            for (int nt = 0; nt < 4; ++nt) {
                int col = j0 + nbase + nt * 16 + lm;
                float val = acc[mt][nt][r];
                if (is_xh) xh_raw[row * 256 + col] = val;
                else       z_silu[row * 256 + col - 256] = silu_fast(val);
            }
        }
    }
}

// ---------------------------------------------------------------------------
// K4: xdbl = conv_silu(xh) @ W_x tiled GEMM (fp32). grid 256, block 256
// ---------------------------------------------------------------------------
__global__ __launch_bounds__(256) void k4_xdbl(
    const float* __restrict__ xh_raw, const float* __restrict__ conv_w,
    const float* __restrict__ conv_b, const float* __restrict__ W_x,
    float* __restrict__ xdbl)
{
    __shared__ float xcs[128][68];
    __shared__ float wxs[64 * 40];
    __shared__ float cw0[256], cw1[256], cbs[256];
    const int tid = threadIdx.x;
    cw0[tid] = conv_w[2 * tid];
    cw1[tid] = conv_w[2 * tid + 1];
    cbs[tid] = conv_b[tid];

    const int R0 = blockIdx.x * 128;
    const int tc = tid & 7;
    const int tr = tid >> 3;

    float acc[4][5];
    #pragma unroll
    for (int i = 0; i < 4; ++i)
        #pragma unroll
        for (int j = 0; j < 5; ++j) acc[i][j] = 0.0f;

    for (int kc = 0; kc < 256; kc += 64) {
        __syncthreads();
        #pragma unroll
        for (int it = 0; it < 3; ++it) {
            int i4 = tid + it * 256;
            if (i4 < 640) ((float4*)wxs)[i4] = ((const float4*)&W_x[kc * 40])[i4];
        }
        #pragma unroll
        for (int it = 0; it < 8; ++it) {
            int idx = tid + it * 256;
            int r = idx >> 4, qq = idx & 15;
            int row = R0 + r;
            float4 cur = *(const float4*)&xh_raw[row * 256 + kc + qq * 4];
            float4 prv = make_float4(0.f, 0.f, 0.f, 0.f);
            if ((row & 4095) != 0)
                prv = *(const float4*)&xh_raw[(row - 1) * 256 + kc + qq * 4];
            int d = kc + qq * 4;
            float4 o;
            o.x = silu_fast(prv.x * cw0[d+0] + cur.x * cw1[d+0] + cbs[d+0]);
            o.y = silu_fast(prv.y * cw0[d+1] + cur.y * cw1[d+1] + cbs[d+1]);
            o.z = silu_fast(prv.z * cw0[d+2] + cur.z * cw1[d+2] + cbs[d+2]);
            o.w = silu_fast(prv.w * cw0[d+3] + cur.w * cw1[d+3] + cbs[d+3]);
            *(float4*)&xcs[r][qq * 4] = o;
        }
        __syncthreads();
        #pragma unroll 2
        for (int k = 0; k < 64; ++k) {
            float wv[5];
            #pragma unroll
            for (int j = 0; j < 5; ++j) wv[j] = wxs[k * 40 + tc * 5 + j];
            #pragma unroll
            for (int i = 0; i < 4; ++i) {
                float a = xcs[tr * 4 + i][k];
                #pragma unroll
                for (int j = 0; j < 5; ++j) acc[i][j] = fmaf(a, wv[j], acc[i][j]);
            }
        }
    }
    #pragma unroll
    for (int i = 0; i < 4; ++i) {
        int row = R0 + tr * 4 + i;
        #pragma unroll
        for (int j = 0; j < 5; ++j) xdbl[row * 40 + tc * 5 + j] = acc[i][j];
    }
}

// ---------------------------------------------------------------------------
// Scan pass 1: local h + decay product P. xdbl read via block-uniform
// addresses (scalar loads). grid (NCH, BATCH), block 256
// ---------------------------------------------------------------------------
__global__ __launch_bounds__(256) void k6_scan1(
    const float* __restrict__ xh_raw, const float* __restrict__ xdbl,
    const float* __restrict__ conv_w, const float* __restrict__ conv_b,
    const float* __restrict__ W_dt, const float* __restrict__ b_dt,
    const float* __restrict__ A_log,
    float* __restrict__ hend, float* __restrict__ Pprod)
{
    const int d = threadIdx.x;
    const int chunk = blockIdx.x;
    const int b = blockIdx.y;
    const int t0 = b * LSEQ + chunk * TCH;

    float A[16];
    #pragma unroll
    for (int qq = 0; qq < 4; ++qq) {
        float4 al = *(const float4*)&A_log[d * 16 + qq * 4];
        A[qq*4+0] = -__expf(al.x); A[qq*4+1] = -__expf(al.y);
        A[qq*4+2] = -__expf(al.z); A[qq*4+3] = -__expf(al.w);
    }
    bool fast = true;
    #pragma unroll
    for (int n = 1; n < 16; ++n)
        fast = fast && (fabsf(A[n] - (n + 1) * A[0]) <= 1e-4f * fabsf(A[n]) + 1e-7f);

    float wdt[8];
    #pragma unroll
    for (int r = 0; r < 8; ++r) wdt[r] = W_dt[r * 256 + d];
    const float bdt = b_dt[d];
    const float w0 = conv_w[2 * d], w1 = conv_w[2 * d + 1], cb = conv_b[d];

    float h[16];
    #pragma unroll
    for (int n = 0; n < 16; ++n) h[n] = 0.f;
    float dtsum = 0.f;

    float prev = (chunk > 0) ? xh_raw[(t0 - 1) * 256 + d] : 0.f;

    for (int tt = 0; tt < TCH; ++tt) {
        const int row = t0 + tt;
        float cur = xh_raw[row * 256 + d];
        float xcv = silu_fast(prev * w0 + cur * w1 + cb);
        prev = cur;

        const float* xr = xdbl + row * 40;    // block-uniform -> scalar loads
        float dtr = bdt;
        #pragma unroll
        for (int r = 0; r < 8; ++r) dtr = fmaf(xr[r], wdt[r], dtr);
        float dtv = softplus_fast(dtr);
        dtsum += dtv;

        float dA[16];
        dA_powers(dtv, A, fast, dA);
        float dtx = dtv * xcv;
        #pragma unroll
        for (int n = 0; n < 16; ++n)
            h[n] = fmaf(dA[n], h[n], dtx * xr[8 + n]);
    }

    float P[16];
    dA_powers(dtsum, A, fast, P);
    const int base = ((b * NCH + chunk) * 256 + d) * 16;
    #pragma unroll
    for (int qq = 0; qq < 4; ++qq) {
        *(float4*)&hend[base + qq * 4] = make_float4(h[qq*4], h[qq*4+1], h[qq*4+2], h[qq*4+3]);
        *(float4*)&Pprod[base + qq * 4] = make_float4(P[qq*4], P[qq*4+1], P[qq*4+2], P[qq*4+3]);
    }
}

// ---------------------------------------------------------------------------
// Scan pass 2: sequential combine; hx: hend -> hin in-place. grid 128x256
// ---------------------------------------------------------------------------
__global__ __launch_bounds__(256) void k7_combine(
    const float* __restrict__ Pp, float* __restrict__ hx)
{
    const int idx = blockIdx.x * 256 + threadIdx.x;   // b*4096 + d*16 + n
    const int b = idx >> 12;
    const int rem = idx & 4095;
    int o = ((b * NCH) << 12) + rem;
    float h = 0.f;
    float P = Pp[o], E = hx[o];
    for (int c = 0; c < NCH; ++c) {
        int on = o + 4096;
        float Pn = 0.f, En = 0.f;
        if (c < NCH - 1) { Pn = Pp[on]; En = hx[on]; }
        hx[o] = h;
        h = fmaf(P, h, E);
        P = Pn; E = En; o = on;
    }
}

// ---------------------------------------------------------------------------
// Scan pass 3: replay with h_in, y = (scan + xc*D) * z_silu -> ybf (bf16).
// grid (NCH, BATCH), block 256
// ---------------------------------------------------------------------------
__global__ __launch_bounds__(256) void k8_scan2(
    const float* __restrict__ xh_raw, const float* __restrict__ xdbl,
    const float* __restrict__ conv_w, const float* __restrict__ conv_b,
    const float* __restrict__ W_dt, const float* __restrict__ b_dt,
    const float* __restrict__ A_log, const float* __restrict__ Dvec,
    const float* __restrict__ hin, const float* __restrict__ zsilu,
    unsigned short* __restrict__ ybf)
{
    const int d = threadIdx.x;
    const int chunk = blockIdx.x;
    const int b = blockIdx.y;
    const int t0 = b * LSEQ + chunk * TCH;

    float A[16];
    #pragma unroll
    for (int qq = 0; qq < 4; ++qq) {
        float4 al = *(const float4*)&A_log[d * 16 + qq * 4];
        A[qq*4+0] = -__expf(al.x); A[qq*4+1] = -__expf(al.y);
        A[qq*4+2] = -__expf(al.z); A[qq*4+3] = -__expf(al.w);
    }
    bool fast = true;
    #pragma unroll
    for (int n = 1; n < 16; ++n)
        fast = fast && (fabsf(A[n] - (n + 1) * A[0]) <= 1e-4f * fabsf(A[n]) + 1e-7f);

    float wdt[8];
    #pragma unroll
    for (int r = 0; r < 8; ++r) wdt[r] = W_dt[r * 256 + d];
    const float bdt = b_dt[d];
    const float w0 = conv_w[2 * d], w1 = conv_w[2 * d + 1], cb = conv_b[d];
    const float Dd = Dvec[d];

    float h[16];
    const int hbase = ((b * NCH + chunk) * 256 + d) * 16;
    #pragma unroll
    for (int qq = 0; qq < 4; ++qq) {
        float4 hv = *(const float4*)&hin[hbase + qq * 4];
        h[qq*4+0] = hv.x; h[qq*4+1] = hv.y; h[qq*4+2] = hv.z; h[qq*4+3] = hv.w;
    }

    float prev = (chunk > 0) ? xh_raw[(t0 - 1) * 256 + d] : 0.f;

    for (int tt = 0; tt < TCH; ++tt) {
        const int row = t0 + tt;
        float cur = xh_raw[row * 256 + d];
        float xcv = silu_fast(prev * w0 + cur * w1 + cb);
        prev = cur;

        const float* xr = xdbl + row * 40;    // block-uniform -> scalar loads
        float dtr = bdt;
        #pragma unroll
        for (int r = 0; r < 8; ++r) dtr = fmaf(xr[r], wdt[r], dtr);
        float dtv = softplus_fast(dtr);

        float dA[16];
        dA_powers(dtv, A, fast, dA);
        float dtx = dtv * xcv;
        float yv = 0.f;
        #pragma unroll
        for (int n = 0; n < 16; ++n) {
            h[n] = fmaf(dA[n], h[n], dtx * xr[8 + n]);
            yv = fmaf(h[n], xr[24 + n], yv);
        }
        yv = fmaf(Dd, xcv, yv);
        const int oidx = row * 256 + d;
        ybf[oidx] = f2bf(yv * zsilu[oidx]);
    }
}

// ---------------------------------------------------------------------------
// K9 (MFMA bf16): out_mm[b,c,l] = sum_k y[b,l,k] * W_out[k,c].
// A <- Wt_out[c][k] direct; B <- ybf[l][k] direct. Epilogue: GN partial sums
// (fused k10a) via wave-reduce + atomicAdd into part (zeroed by k0).
// grid 256, block 256
// ---------------------------------------------------------------------------
__global__ __launch_bounds__(256) void k9_gemm_out(
    const unsigned short* __restrict__ ybf, const unsigned short* __restrict__ wtout,
    float* __restrict__ out_mm, float* __restrict__ part)
{
    __shared__ __align__(16) unsigned short Abf[128 * LSTR];   // rows = c
    __shared__ __align__(16) unsigned short Bbf[128 * LSTR];   // rows = l
    const int tid = threadIdx.x;
    const int R0 = blockIdx.x * 128;
    const int b  = R0 >> 12;
    const int l0 = R0 & 4095;

    const int w    = tid >> 6;
    const int lane = tid & 63;
    const int lm   = lane & 15;
    const int q    = lane >> 4;
    const int mbase = (w & 1) * 64;           // c-quadrant
    const int nbase = (w >> 1) * 64;          // l-quadrant

    f32x4 acc[4][4];
    #pragma unroll
    for (int i = 0; i < 4; ++i)
        #pragma unroll
        for (int j = 0; j < 4; ++j) acc[i][j] = (f32x4){0.f, 0.f, 0.f, 0.f};

    for (int kc = 0; kc < 256; kc += 64) {
        __syncthreads();
        #pragma unroll
        for (int it = 0; it < 4; ++it) {
            int slot = tid + it * 256;        // 128 rows x 8 segs
            int r = slot >> 3, seg = slot & 7;
            short8 va = *(const short8*)&wtout[(size_t)r * 256 + kc + seg * 8];
            *(short8*)&Abf[r * LSTR + seg * 8] = va;
            short8 vb = *(const short8*)&ybf[(size_t)(R0 + r) * 256 + kc + seg * 8];
            *(short8*)&Bbf[r * LSTR + seg * 8] = vb;
        }
        __syncthreads();
        #pragma unroll
        for (int kt = 0; kt < 2; ++kt) {
            short8 af[4], bfr[4];
            #pragma unroll
            for (int mt = 0; mt < 4; ++mt)
                af[mt] = *(const short8*)&Abf[(mbase + mt * 16 + lm) * LSTR + kt * 32 + q * 8];
            #pragma unroll
            for (int nt = 0; nt < 4; ++nt)
                bfr[nt] = *(const short8*)&Bbf[(nbase + nt * 16 + lm) * LSTR + kt * 32 + q * 8];
            #pragma unroll
            for (int mt = 0; mt < 4; ++mt)
                #pragma unroll
                for (int nt = 0; nt < 4; ++nt)
                    acc[mt][nt] = __builtin_amdgcn_mfma_f32_16x16x32_bf16(
                        af[mt], bfr[nt], acc[mt][nt], 0, 0, 0);
        }
    }

    #pragma unroll
    for (int mt = 0; mt < 4; ++mt) {
        #pragma unroll
        for (int r = 0; r < 4; ++r) {
            int c = mbase + mt * 16 + q * 4 + r;
            long base = (long)(b * 128 + c) * 4096 + l0;
            #pragma unroll
            for (int nt = 0; nt < 4; ++nt)
                out_mm[base + nbase + nt * 16 + lm] = acc[mt][nt][r];
        }
    }

    // fused GroupNorm partial sums: groups g0 = mbase>>5 (mt 0,1), g0+1 (mt 2,3)
    float s0 = 0.f, q0 = 0.f, s1 = 0.f, q1 = 0.f;
    #pragma unroll
    for (int mt = 0; mt < 4; ++mt)
        #pragma unroll
        for (int nt = 0; nt < 4; ++nt)
            #pragma unroll
            for (int r = 0; r < 4; ++r) {
                float v = acc[mt][nt][r];
                if (mt < 2) { s0 += v; q0 += v * v; }
                else        { s1 += v; q1 += v * v; }
            }
    #pragma unroll
    for (int off = 32; off > 0; off >>= 1) {
        s0 += __shfl_down(s0, off, 64);
        q0 += __shfl_down(q0, off, 64);
        s1 += __shfl_down(s1, off, 64);
        q1 += __shfl_down(q1, off, 64);
    }
    if (lane == 0) {
        int g0 = mbase >> 5;
        atomicAdd(&part[(b * 4 + g0) * 2],     s0);
        atomicAdd(&part[(b * 4 + g0) * 2 + 1], q0);
        atomicAdd(&part[(b * 4 + g0 + 1) * 2],     s1);
        atomicAdd(&part[(b * 4 + g0 + 1) * 2 + 1], q1);
    }
}

// K10b: finalize mean / rsqrt(var+eps) per (b,g). grid 1, block 64
__global__ void k10b_gnstat(const float* __restrict__ part, float* __restrict__ stat)
{
    const int tid = threadIdx.x;
    if (tid < 32) {
        float S = part[tid * 2];
        float Q = part[tid * 2 + 1];
        const float inv_n = 1.0f / 131072.0f;
        float mean = S * inv_n;
        float var  = Q * inv_n - mean * mean;
        stat[tid * 2]     = mean;
        stat[tid * 2 + 1] = rsqrtf(var + 1e-5f);
    }
}

// K10c: apply GN + silu + residual. grid 4096, block 256
__global__ __launch_bounds__(256) void k10c_apply(
    const float* __restrict__ out_mm, const float* __restrict__ stat,
    const float* __restrict__ gamma, const float* __restrict__ beta,
    const float* __restrict__ x_hsi, float* __restrict__ out)
{
    const int idx4 = blockIdx.x * 256 + threadIdx.x;
    const int flat = idx4 * 4;
    const int c = (flat >> 12) & 127;
    const int b = flat >> 19;
    const int g = c >> 5;
    const float mean = stat[(b * 4 + g) * 2];
    const float inv  = stat[(b * 4 + g) * 2 + 1];
    const float ga = gamma[c], be = beta[c];
    float4 v = *(const float4*)&out_mm[flat];
    float4 r = *(const float4*)&x_hsi[flat];
    float o[4];
    float vv[4] = {v.x, v.y, v.z, v.w};
    float rr[4] = {r.x, r.y, r.z, r.w};
    #pragma unroll
    for (int qq = 0; qq < 4; ++qq) {
        float xn = (vv[qq] - mean) * inv;
        float gv = xn * ga + be;
        o[qq] = silu_fast(gv) + rr[qq];
    }
    *(float4*)&out[flat] = make_float4(o[0], o[1], o[2], o[3]);
}

// ---------------------------------------------------------------------------
extern "C" void kernel_launch(void* const* d_in, const int* in_sizes, int n_in,
                              void* d_out, int out_size, void* d_ws, size_t ws_size,
                              hipStream_t stream)
{
    const float* x_hsi  = (const float*)d_in[0];
    const float* W_in   = (const float*)d_in[1];
    const float* conv_w = (const float*)d_in[2];
    const float* conv_b = (const float*)d_in[3];
    const float* W_x    = (const float*)d_in[4];
    const float* W_dt   = (const float*)d_in[5];
    const float* b_dt   = (const float*)d_in[6];
    const float* A_log  = (const float*)d_in[7];
    const float* Dv     = (const float*)d_in[8];
    const float* W_out  = (const float*)d_in[9];
    const float* gnw    = (const float*)d_in[10];
    const float* gnb    = (const float*)d_in[11];

    float* ws = (float*)d_ws;
    float* xh_raw = ws + 0;            // 8,388,608
    float* zsilu  = ws + 8388608;      // 8,388,608
    float* out_mm = ws + 16777216;     // 4,194,304
    float* xdbl   = ws + 20971520;     // 1,310,720
    float* hx     = ws + 22282240;     // 4,194,304  hend -> hin (in-place)
    float* Pp     = ws + 26476544;     // 4,194,304
    float* part   = ws + 30670848;     // 64
    float* stat   = ws + 30670912;     // 64
    unsigned short* xbf   = (unsigned short*)(ws + 30671104);  // 4,194,304 us
    unsigned short* wtin  = (unsigned short*)(ws + 32768256);  // 65,536 us
    unsigned short* wtout = (unsigned short*)(ws + 32801024);  // 32,768 us
    unsigned short* ybf   = (unsigned short*)(ws + 32817408);  // 4,194,304 us
    float* outp   = (float*)d_out;

    k0_setup<<<1049, 256, 0, stream>>>(x_hsi, W_in, W_out, xbf, wtin, wtout, part);
    k1_gemm_in<<<dim3(256, 4), 256, 0, stream>>>(xbf, wtin, xh_raw, zsilu);
    k4_xdbl<<<256, 256, 0, stream>>>(xh_raw, conv_w, conv_b, W_x, xdbl);
    k6_scan1<<<dim3(NCH, BATCH), 256, 0, stream>>>(xh_raw, xdbl, conv_w, conv_b,
                                                   W_dt, b_dt, A_log, hx, Pp);
    k7_combine<<<128, 256, 0, stream>>>(Pp, hx);
    k8_scan2<<<dim3(NCH, BATCH), 256, 0, stream>>>(xh_raw, xdbl, conv_w, conv_b,
                                                   W_dt, b_dt, A_log, Dv, hx, zsilu, ybf);
    k9_gemm_out<<<256, 256, 0, stream>>>(ybf, wtout, out_mm, part);
    k10b_gnstat<<<1, 64, 0, stream>>>(part, stat);
    k10c_apply<<<4096, 256, 0, stream>>>(out_mm, stat, gnw, gnb, x_hsi, outp);
}